// Round 9
// baseline (1710.882 us; speedup 1.0000x reference)
//
#include <hip/hip_runtime.h>
#include <hip/hip_bf16.h>
#include <math.h>

typedef short bf16x8 __attribute__((ext_vector_type(8)));
typedef float f32x4 __attribute__((ext_vector_type(4)));
typedef short short4v __attribute__((ext_vector_type(4)));
typedef short short8v __attribute__((ext_vector_type(8)));

__device__ __forceinline__ short f2bf(float f) {
  unsigned u = __builtin_bit_cast(unsigned, f);
  unsigned r = (u + 0x7FFFu + ((u >> 16) & 1u)) >> 16;
  return (short)r;
}
__device__ __forceinline__ float bf2f(short s) {
  unsigned u = ((unsigned)(unsigned short)s) << 16;
  return __builtin_bit_cast(float, u);
}

typedef __attribute__((address_space(1))) const unsigned g_u32;
typedef __attribute__((address_space(3))) unsigned l_u32;
__device__ __forceinline__ void gload_lds16(const short* g, short* l) {
  __builtin_amdgcn_global_load_lds((g_u32*)g, (l_u32*)l, 16, 0, 0);
}

#define VMCNT(n) asm volatile("s_waitcnt vmcnt(" #n ")" ::: "memory")

// ---------------- casts ----------------

__global__ __launch_bounds__(256) void k_cast_x(const float* __restrict__ x, short* __restrict__ xb) {
  int tid = blockIdx.x * 256 + threadIdx.x;
  int d4 = tid & 255;
  int sb = tid >> 8;
  int s = sb & 2047;
  int b = sb >> 11;
  float4 v = *((const float4*)(x + (((size_t)s * 8 + b) << 10)) + d4);
  short4v o;
  o.x = f2bf(v.x); o.y = f2bf(v.y); o.z = f2bf(v.z); o.w = f2bf(v.w);
  *((short4v*)(xb + (((size_t)b * 2048 + s) << 10)) + d4) = o;
}

__global__ __launch_bounds__(256) void k_cast_w(const float* __restrict__ Wq, const float* __restrict__ Wk,
                                                const float* __restrict__ Wv, short* __restrict__ Wcat) {
  int tid = blockIdx.x * 256 + threadIdx.x;
  int d4 = tid & 255;
  int n = tid >> 8;
  const float* src = (n < 1024) ? Wq : (n < 2048 ? Wk : Wv);
  int nl = n & 1023;
  float4 v = *((const float4*)(src + ((size_t)nl << 10)) + d4);
  short4v o;
  o.x = f2bf(v.x); o.y = f2bf(v.y); o.z = f2bf(v.z); o.w = f2bf(v.w);
  *((short4v*)(Wcat + ((size_t)n << 10)) + d4) = o;
}

__global__ __launch_bounds__(256) void k_cast_bias(const float* __restrict__ bq, const float* __restrict__ bk,
                                                   const float* __restrict__ bv, float* __restrict__ biascat) {
  int i = blockIdx.x * 256 + threadIdx.x;
  if (i < 3072) biascat[i] = (i < 1024) ? bq[i] : (i < 2048 ? bk[i & 1023] : bv[i & 1023]);
}

// ---------------- 256x256-tile GEMM core: 80KB LDS (A-ring 3 + B-ring 2) ----------------
// C[256][256] = A[256, K-contig, LDA] * B^T[256, K-contig, LDB]
// 512 threads = 8 waves (2M x 4N); per-wave 128x64 -> acc[8][4] f32x4 (16x16x32 MFMA).
// LDS: A ring of 3 chunk-slots + B ring of 2, each [256 rows][32 k] bf16 = 16KB
// -> 80KB total -> 2 blocks/CU co-resident (the cross-block overlap fills the
// barrier-serialized port/MFMA gaps; m114 mechanism). Fragment pattern + slot
// swizzle identical to R8 (slot ^= (row>>1)&3; PMC-verified 0 conflicts).
// Per chunk c (2 phases):
//  p1: rdA(c,mh0)+rdB(c)                     -> MFMA mh0
//  p2: rdA(c,mh1), stage_pair(c+2), VMCNT(4) -> MFMA mh1
// Ledger (verified): entering p1(c) outstanding = pair(c+1) [4 loads]; p2 issues
// pair(c+2) [8]; VMCNT(4) drains pair(c+1) (needed next phase, issued 2 phases ago)
// and keeps pair(c+2) in flight. Slot overwrites are >=2 barriers after the last
// reader. Prologue: pair(0), pair(1), VMCNT(4). Epilogue: VMCNT(0) at c=NC-2.
template <int LDA, int LDB>
__device__ __forceinline__ void gemm256_core(const short* __restrict__ Ag, const short* __restrict__ Bg,
                                             int NT, short* __restrict__ lds, f32x4 (&acc)[8][4], int tid) {
  const int lane = tid & 63;
  const int wid = tid >> 6;
  const int wm = wid >> 2, wn = wid & 3;
  const int r15 = lane & 15;
  const int g = lane >> 4;
  const int co = ((g ^ ((r15 >> 1) & 3)) << 3);
  short* As = lds;               // 3 slots x 8192 shorts
  short* Bs = lds + 3 * 8192;    // 2 slots x 8192 shorts

  const int abase = (wm * 128 + r15) * 32 + co;
  const int bbase = (wn * 64 + r15) * 32 + co;

  auto stage_pair = [&](int c) {   // stage A(c) then B(c): 4 gload_lds per thread
    short* Ap = As + (c % 3) * 8192;
    short* Bp = Bs + (c & 1) * 8192;
    int kb = c << 5;
#pragma unroll
    for (int i = 0; i < 2; ++i) {
      int ch = i * 512 + tid;
      int r = ch >> 2, s = ch & 3;
      gload_lds16(Ag + (size_t)r * LDA + kb + ((s ^ ((r >> 1) & 3)) << 3), Ap + ch * 8);
    }
#pragma unroll
    for (int i = 0; i < 2; ++i) {
      int ch = i * 512 + tid;
      int r = ch >> 2, s = ch & 3;
      gload_lds16(Bg + (size_t)r * LDB + kb + ((s ^ ((r >> 1) & 3)) << 3), Bp + ch * 8);
    }
  };

  bf16x8 a4[4], br[4];
  auto rdA = [&](int c, int mh) {
    const short* p = As + (c % 3) * 8192 + abase + (mh << 11);
#pragma unroll
    for (int mf = 0; mf < 4; ++mf) a4[mf] = *(const bf16x8*)(p + mf * 512);
  };
  auto rdB = [&](int c) {
    const short* p = Bs + (c & 1) * 8192 + bbase;
#pragma unroll
    for (int nf = 0; nf < 4; ++nf) br[nf] = *(const bf16x8*)(p + nf * 512);
  };
  auto mm = [&](int mh) {
    __builtin_amdgcn_s_barrier();
    asm volatile("s_waitcnt lgkmcnt(0)" ::: "memory");
    __builtin_amdgcn_sched_barrier(0);
    __builtin_amdgcn_s_setprio(1);
#pragma unroll
    for (int mf = 0; mf < 4; ++mf)
#pragma unroll
      for (int nf = 0; nf < 4; ++nf)
        acc[mh * 4 + mf][nf] =
            __builtin_amdgcn_mfma_f32_16x16x32_bf16(a4[mf], br[nf], acc[mh * 4 + mf][nf], 0, 0, 0);
    __builtin_amdgcn_s_setprio(0);
    __builtin_amdgcn_s_barrier();
  };

  const int NC = 2 * NT;
  // prologue: chunks 0,1 staged; drain pair(0), keep pair(1) in flight
  stage_pair(0);
  stage_pair(1);
  VMCNT(4);
  __builtin_amdgcn_s_barrier();

  for (int c = 0; c < NC - 2; ++c) {
    rdA(c, 0); rdB(c);
    mm(0);
    rdA(c, 1); stage_pair(c + 2); VMCNT(4);
    mm(1);
  }
  {  // c = NC-2: nothing left to stage; drain pair(NC-1)
    const int c = NC - 2;
    rdA(c, 0); rdB(c);
    mm(0);
    rdA(c, 1); VMCNT(0);
    mm(1);
  }
  {  // c = NC-1
    const int c = NC - 1;
    rdA(c, 0); rdB(c);
    mm(0);
    rdA(c, 1);
    mm(1);
  }
}

// ---------------- QKV projection: (16384,3072) = Xb (16384,1024) * Wcat^T + bias ----------------
// Q, K stored (B,S,A) bf16; V stored TRANSPOSED as Vt (B,A,S) bf16.
__global__ __launch_bounds__(512, 4) void k_proj(const short* __restrict__ Xb, const short* __restrict__ Wc,
                                                 const float* __restrict__ biascat,
                                                 short* __restrict__ Q, short* __restrict__ K, short* __restrict__ Vt) {
  __shared__ __align__(16) short lds[40960];   // 80 KiB
  int tid = threadIdx.x;
  int wg = blockIdx.x;                       // 768 blocks
  int swz = (wg & 7) * 96 + (wg >> 3);       // XCD swizzle (768 % 8 == 0, bijective)
  int mt = swz / 12, nt = swz % 12;
  int m0 = mt << 8, n0 = nt << 8;
  f32x4 acc[8][4] = {};
  gemm256_core<1024, 1024>(Xb + (size_t)m0 * 1024, Wc + (size_t)n0 * 1024, 16, lds, acc, tid);
  int lane = tid & 63, wid = tid >> 6;
  int wm = wid >> 2, wn = wid & 3;
  int r15 = lane & 15;
  int which = n0 >> 10;
  int nbase = n0 & 1023;
  if (which == 2) {
#pragma unroll
    for (int ni = 0; ni < 4; ++ni) {
      int cth = wn * 64 + ni * 16 + r15;
      int a = nbase + cth;
      float bv = biascat[n0 + cth];
#pragma unroll
      for (int mi = 0; mi < 8; ++mi) {
        int r = m0 + wm * 128 + mi * 16 + ((lane >> 4) << 2);
        int b = r >> 11, s = r & 2047;
        short4v o;
#pragma unroll
        for (int j = 0; j < 4; ++j) o[j] = f2bf(acc[mi][ni][j] + bv);
        *(short4v*)(Vt + ((size_t)b << 21) + ((size_t)a << 11) + s) = o;
      }
    }
  } else {
    short* outb = (which == 0) ? Q : K;
#pragma unroll
    for (int ni = 0; ni < 4; ++ni) {
      int cth = wn * 64 + ni * 16 + r15;
      float bv = biascat[n0 + cth];
#pragma unroll
      for (int mi = 0; mi < 8; ++mi)
#pragma unroll
        for (int j = 0; j < 4; ++j) {
          int r = m0 + wm * 128 + mi * 16 + ((lane >> 4) << 2) + j;
          outb[((size_t)r << 10) + nbase + cth] = f2bf(acc[mi][ni][j] + bv);
        }
    }
  }
}

// ---------------- QK^T: causal lower-tri 256-tiles, compact triangular grid ----------------
// 288 blocks = 36 (mt,nt) tri-jobs x 8 batches; XCD-bijective swizzle gives
// each XCD one whole batch (L2 locality on Q/K panels).
__global__ __launch_bounds__(512, 4) void k_qk(const short* __restrict__ Q, const short* __restrict__ K,
                                               short* __restrict__ Sc) {
  __shared__ __align__(16) short lds[40960];
  int f = blockIdx.x;                        // 0..287
  int swz = (f & 7) * 36 + (f >> 3);         // XCD x -> swz in [36x, 36x+36) -> batch x
  int b = swz / 36;
  int t = swz % 36;
  int mt = (int)((sqrtf(8.f * t + 1.f) - 1.f) * 0.5f);
  while ((mt + 1) * (mt + 2) / 2 <= t) ++mt;
  while (mt * (mt + 1) / 2 > t) --mt;
  int nt = t - mt * (mt + 1) / 2;
  int tid = threadIdx.x;
  int m0 = mt << 8, n0 = nt << 8;
  const short* Qb = Q + ((size_t)b << 21);
  const short* Kb = K + ((size_t)b << 21);
  f32x4 acc[8][4] = {};
  gemm256_core<1024, 1024>(Qb + (size_t)m0 * 1024, Kb + (size_t)n0 * 1024, 16, lds, acc, tid);
  short* Sb = Sc + ((size_t)b << 22);
  int lane = tid & 63, wid = tid >> 6;
  int wm = wid >> 2, wn = wid & 3;
  int r15 = lane & 15;
#pragma unroll
  for (int mi = 0; mi < 8; ++mi)
#pragma unroll
    for (int ni = 0; ni < 4; ++ni)
#pragma unroll
      for (int j = 0; j < 4; ++j) {
        int r = m0 + wm * 128 + mi * 16 + ((lane >> 4) << 2) + j;
        int c = n0 + wn * 64 + ni * 16 + r15;
        Sb[((size_t)r << 11) + c] = f2bf(acc[mi][ni][j] * 0.03125f);
      }
}

// ---------------- row softmax in-place, causal; zero-fill to 256-tile edge ----------------
__global__ __launch_bounds__(256) void k_softmax(short* __restrict__ Sc) {
  int row = blockIdx.x;
  int b = row >> 11, q = row & 2047;
  short* Pr = Sc + ((size_t)b << 22) + ((size_t)q << 11);
  int T = ((q >> 8) + 1) << 8;          // padded causal length (multiple of 256)
  int tid = threadIdx.x, lane = tid & 63, wid = tid >> 6;
  int k0 = tid << 3;
  float v[8];
  if (k0 < T) {
    short8v raw = *(const short8v*)(Pr + k0);
#pragma unroll
    for (int j = 0; j < 8; ++j) v[j] = (k0 + j <= q) ? bf2f(raw[j]) : -__builtin_inff();
  } else {
#pragma unroll
    for (int j = 0; j < 8; ++j) v[j] = -__builtin_inff();
  }
  float mx = v[0];
#pragma unroll
  for (int j = 1; j < 8; ++j) mx = fmaxf(mx, v[j]);
  for (int off = 1; off < 64; off <<= 1) mx = fmaxf(mx, __shfl_xor(mx, off, 64));
  __shared__ float red[2][4];
  if (lane == 0) red[0][wid] = mx;
  __syncthreads();
  mx = fmaxf(fmaxf(red[0][0], red[0][1]), fmaxf(red[0][2], red[0][3]));
  float e[8], sum = 0.f;
#pragma unroll
  for (int j = 0; j < 8; ++j) {
    e[j] = exp2f((v[j] - mx) * 1.4426950408889634f);
    sum += e[j];
  }
  for (int off = 1; off < 64; off <<= 1) sum += __shfl_xor(sum, off, 64);
  if (lane == 0) red[1][wid] = sum;
  __syncthreads();
  sum = red[1][0] + red[1][1] + red[1][2] + red[1][3];
  float inv = 1.f / sum;
  if (k0 < T) {
    short8v o;
#pragma unroll
    for (int j = 0; j < 8; ++j) o[j] = (k0 + j <= q) ? f2bf(e[j] * inv) : (short)0;
    *(short8v*)(Pr + k0) = o;
  }
}

// ---------------- PV: out (S,B,A) f32 = P (B,S,S) * Vt (B,A,S)^T ----------------
// 256 blocks, XCD-bijective swizzle: XCD x gets batch x (Vt panel L2 locality).
__global__ __launch_bounds__(512, 4) void k_pv(const short* __restrict__ P, const short* __restrict__ Vt,
                                               float* __restrict__ out) {
  __shared__ __align__(16) short lds[40960];
  int f = blockIdx.x;                        // 0..255
  int swz = (f & 7) * 32 + (f >> 3);         // XCD x -> swz in [32x, 32x+32) -> batch x
  int nt = swz & 3;
  int mt = (swz >> 2) & 7;
  int b = swz >> 5;
  int tid = threadIdx.x;
  int m0 = mt << 8, n0 = nt << 8;
  const short* Pb = P + ((size_t)b << 22);
  const short* Vtb = Vt + ((size_t)b << 21);
  f32x4 acc[8][4] = {};
  gemm256_core<2048, 2048>(Pb + (size_t)m0 * 2048, Vtb + (size_t)n0 * 2048, 4 * (mt + 1), lds, acc, tid);
  int lane = tid & 63, wid = tid >> 6;
  int wm = wid >> 2, wn = wid & 3;
  int r15 = lane & 15;
#pragma unroll
  for (int mi = 0; mi < 8; ++mi)
#pragma unroll
    for (int ni = 0; ni < 4; ++ni)
#pragma unroll
      for (int j = 0; j < 4; ++j) {
        int r = m0 + wm * 128 + mi * 16 + ((lane >> 4) << 2) + j;  // q
        int c = n0 + wn * 64 + ni * 16 + r15;                      // a
        out[((size_t)r << 13) + ((size_t)b << 10) + c] = acc[mi][ni][j];
      }
}

extern "C" void kernel_launch(void* const* d_in, const int* in_sizes, int n_in,
                              void* d_out, int out_size, void* d_ws, size_t ws_size,
                              hipStream_t stream) {
  const float* x  = (const float*)d_in[0];
  const float* Wq = (const float*)d_in[1];
  const float* bq = (const float*)d_in[2];
  const float* Wk = (const float*)d_in[3];
  const float* bk = (const float*)d_in[4];
  const float* Wv = (const float*)d_in[5];
  const float* bv = (const float*)d_in[6];
  float* out = (float*)d_out;
  char* ws = (char*)d_ws;

  short* xb   = (short*)(ws);                    // 33,554,432 B
  short* Wcat = (short*)(ws + 33554432);         //  6,291,456 B
  float* bias = (float*)(ws + 39845888);         //     12,288 B
  short* Q    = (short*)(ws + 39858176);         // 33,554,432 B
  short* K    = (short*)(ws + 73412608);         // 33,554,432 B
  short* Vt   = (short*)(ws + 106967040);        // 33,554,432 B (written transposed by k_proj)
  short* Sc   = (short*)(ws + 140521472);        // 67,108,864 B

  k_cast_x<<<16384, 256, 0, stream>>>(x, xb);
  k_cast_w<<<3072, 256, 0, stream>>>(Wq, Wk, Wv, Wcat);
  k_cast_bias<<<12, 256, 0, stream>>>(bq, bk, bv, bias);
  k_proj<<<768, 512, 0, stream>>>(xb, Wcat, bias, Q, K, Vt);
  k_qk<<<288, 512, 0, stream>>>(Q, K, Sc);
  k_softmax<<<16384, 256, 0, stream>>>(Sc);
  k_pv<<<256, 512, 0, stream>>>(Sc, Vt, out);
}

// Round 10
// 273.885 us; speedup vs baseline: 6.2467x; 6.2467x over previous
//
#include <hip/hip_runtime.h>
#include <hip/hip_bf16.h>
#include <math.h>

typedef short bf16x8 __attribute__((ext_vector_type(8)));
typedef float f32x4 __attribute__((ext_vector_type(4)));
typedef short short4v __attribute__((ext_vector_type(4)));
typedef short short8v __attribute__((ext_vector_type(8)));

__device__ __forceinline__ short f2bf(float f) {
  unsigned u = __builtin_bit_cast(unsigned, f);
  unsigned r = (u + 0x7FFFu + ((u >> 16) & 1u)) >> 16;
  return (short)r;
}
__device__ __forceinline__ float bf2f(short s) {
  unsigned u = ((unsigned)(unsigned short)s) << 16;
  return __builtin_bit_cast(float, u);
}

typedef __attribute__((address_space(1))) const unsigned g_u32;
typedef __attribute__((address_space(3))) unsigned l_u32;
__device__ __forceinline__ void gload_lds16(const short* g, short* l) {
  __builtin_amdgcn_global_load_lds((g_u32*)g, (l_u32*)l, 16, 0, 0);
}

#define VMCNT(n) asm volatile("s_waitcnt vmcnt(" #n ")" ::: "memory")

// ---------------- casts ----------------

__global__ __launch_bounds__(256) void k_cast_x(const float* __restrict__ x, short* __restrict__ xb) {
  int tid = blockIdx.x * 256 + threadIdx.x;
  int d4 = tid & 255;
  int sb = tid >> 8;
  int s = sb & 2047;
  int b = sb >> 11;
  float4 v = *((const float4*)(x + (((size_t)s * 8 + b) << 10)) + d4);
  short4v o;
  o.x = f2bf(v.x); o.y = f2bf(v.y); o.z = f2bf(v.z); o.w = f2bf(v.w);
  *((short4v*)(xb + (((size_t)b * 2048 + s) << 10)) + d4) = o;
}

__global__ __launch_bounds__(256) void k_cast_w(const float* __restrict__ Wq, const float* __restrict__ Wk,
                                                const float* __restrict__ Wv, short* __restrict__ Wcat) {
  int tid = blockIdx.x * 256 + threadIdx.x;
  int d4 = tid & 255;
  int n = tid >> 8;
  const float* src = (n < 1024) ? Wq : (n < 2048 ? Wk : Wv);
  int nl = n & 1023;
  float4 v = *((const float4*)(src + ((size_t)nl << 10)) + d4);
  short4v o;
  o.x = f2bf(v.x); o.y = f2bf(v.y); o.z = f2bf(v.z); o.w = f2bf(v.w);
  *((short4v*)(Wcat + ((size_t)n << 10)) + d4) = o;
}

__global__ __launch_bounds__(256) void k_cast_bias(const float* __restrict__ bq, const float* __restrict__ bk,
                                                   const float* __restrict__ bv, float* __restrict__ biascat) {
  int i = blockIdx.x * 256 + threadIdx.x;
  if (i < 3072) biascat[i] = (i < 1024) ? bq[i] : (i < 2048 ? bk[i & 1023] : bv[i & 1023]);
}

// ---------------- R8 core (VERIFIED 284us config): 256x256 tile, 4-slot rings, 128KB ----------------
template <int LDA, int LDB>
__device__ __forceinline__ void gemm256_core(const short* __restrict__ Ag, const short* __restrict__ Bg,
                                             int NT, short* __restrict__ lds, f32x4 (&acc)[8][4], int tid) {
  const int lane = tid & 63;
  const int wid = tid >> 6;
  const int wm = wid >> 2, wn = wid & 3;
  const int r15 = lane & 15;
  const int g = lane >> 4;
  const int co = ((g ^ ((r15 >> 1) & 3)) << 3);
  short* As = lds;
  short* Bs = lds + 32768;

  const int abase = (wm * 128 + r15) * 32 + co;
  const int bbase = (wn * 64 + r15) * 32 + co;

  auto stageA = [&](int c) {
    short* Lp = As + ((c & 3) << 13);
    int kb = c << 5;
#pragma unroll
    for (int i = 0; i < 2; ++i) {
      int ch = i * 512 + tid;
      int r = ch >> 2, s = ch & 3;
      gload_lds16(Ag + (size_t)r * LDA + kb + ((s ^ ((r >> 1) & 3)) << 3), Lp + ch * 8);
    }
  };
  auto stageB = [&](int c) {
    short* Lp = Bs + ((c & 3) << 13);
    int kb = c << 5;
#pragma unroll
    for (int i = 0; i < 2; ++i) {
      int ch = i * 512 + tid;
      int r = ch >> 2, s = ch & 3;
      gload_lds16(Bg + (size_t)r * LDB + kb + ((s ^ ((r >> 1) & 3)) << 3), Lp + ch * 8);
    }
  };

  bf16x8 a4[4], br[4];
  auto rdA = [&](int c, int mh) {
    const short* p = As + ((c & 3) << 13) + abase + (mh << 11);
#pragma unroll
    for (int mf = 0; mf < 4; ++mf) a4[mf] = *(const bf16x8*)(p + mf * 512);
  };
  auto rdB = [&](int c) {
    const short* p = Bs + ((c & 3) << 13) + bbase;
#pragma unroll
    for (int nf = 0; nf < 4; ++nf) br[nf] = *(const bf16x8*)(p + nf * 512);
  };
  auto mm = [&](int mh) {
    __builtin_amdgcn_s_barrier();
    asm volatile("s_waitcnt lgkmcnt(0)" ::: "memory");
    __builtin_amdgcn_sched_barrier(0);
    __builtin_amdgcn_s_setprio(1);
#pragma unroll
    for (int mf = 0; mf < 4; ++mf)
#pragma unroll
      for (int nf = 0; nf < 4; ++nf)
        acc[mh * 4 + mf][nf] =
            __builtin_amdgcn_mfma_f32_16x16x32_bf16(a4[mf], br[nf], acc[mh * 4 + mf][nf], 0, 0, 0);
    __builtin_amdgcn_s_setprio(0);
    __builtin_amdgcn_s_barrier();
  };

  stageB(0); stageA(0); stageB(1); stageA(1); stageB(2); stageA(2); stageB(3);
  VMCNT(10);
  __builtin_amdgcn_s_barrier();

  for (int t = 0; t + 2 < NT; ++t) {
    const int c0 = 2 * t, c1 = 2 * t + 1;
    rdA(c0, 0); rdB(c0); stageA(c0 + 3);
    mm(0);
    rdA(c0, 1); stageB(c0 + 4); VMCNT(10);
    mm(1);
    rdA(c1, 0); rdB(c1); stageA(c1 + 3);
    mm(0);
    rdA(c1, 1); stageB(c1 + 4); VMCNT(10);
    mm(1);
  }
  {
    const int c0 = 2 * (NT - 2), c1 = c0 + 1;
    rdA(c0, 0); rdB(c0); stageA(c0 + 3);
    mm(0);
    rdA(c0, 1); VMCNT(8);
    mm(1);
    rdA(c1, 0); rdB(c1);
    mm(0);
    rdA(c1, 1); VMCNT(4);
    mm(1);
  }
  {
    const int c0 = 2 * (NT - 1), c1 = c0 + 1;
    rdA(c0, 0); rdB(c0);
    mm(0);
    rdA(c0, 1); VMCNT(0);
    mm(1);
    rdA(c1, 0); rdB(c1);
    mm(0);
    rdA(c1, 1);
    mm(1);
  }
}

// ---------------- co-residency core: 256x128 tile, 8 waves 4Mx2N, per-wave 64x64 ----------------
// acc[4][4] = 64 regs; LDS = A-ring3 [256][32] (48K) + B-ring3 [128][32] (24K) = 72KB
// -> 2 blocks/CU (144KB LDS, <=128 regs/wave). Cross-block overlap fills the
// barrier-serialized LDS-port/MFMA gaps (m114 mechanism).
// Per chunk c (ONE phase): {rd 4A+4B; stage pair(c+2) [2A+1B loads]; VMCNT(3);
// barrier; lgkm; sched_barrier; 16 MFMA; barrier}. Ring-3 on BOTH operands because
// stage-issue shares the phase with reads: slot (c+2)%3 == (c-1)%3, retired 2 barriers
// ago. Ledger: prologue pair(0),pair(1),VMCNT(3); steady VMCNT(3) drains pair(c+1);
// peel VMCNT(0) at c=NC-2. All K-loop VMEM is gload_lds (homogeneous counting).
template <int LDA, int LDB>
__device__ __forceinline__ void gemm128n_core(const short* __restrict__ Ag, const short* __restrict__ Bg,
                                              int NC, short* __restrict__ lds, f32x4 (&acc)[4][4], int tid) {
  const int lane = tid & 63;
  const int wid = tid >> 6;
  const int wm = wid >> 1, wn = wid & 1;
  const int r15 = lane & 15;
  const int g = lane >> 4;
  const int co = ((g ^ ((r15 >> 1) & 3)) << 3);
  short* As = lds;                 // 3 x 8192 shorts
  short* Bs = lds + 3 * 8192;      // 3 x 4096 shorts

  const int abase = (wm * 64 + r15) * 32 + co;
  const int bbase = (wn * 64 + r15) * 32 + co;

  auto stage_pair = [&](int c) {   // A: 2 loads/thread; B: 1 load/thread
    short* Ap = As + (c % 3) * 8192;
    short* Bp = Bs + (c % 3) * 4096;
    int kb = c << 5;
#pragma unroll
    for (int i = 0; i < 2; ++i) {
      int ch = i * 512 + tid;
      int r = ch >> 2, s = ch & 3;
      gload_lds16(Ag + (size_t)r * LDA + kb + ((s ^ ((r >> 1) & 3)) << 3), Ap + ch * 8);
    }
    {
      int r = tid >> 2, s = tid & 3;
      gload_lds16(Bg + (size_t)r * LDB + kb + ((s ^ ((r >> 1) & 3)) << 3), Bp + tid * 8);
    }
  };

  auto phase = [&](int c, bool stage, bool last) {
    bf16x8 a4[4], br[4];
    const short* pa = As + (c % 3) * 8192 + abase;
    const short* pb = Bs + (c % 3) * 4096 + bbase;
#pragma unroll
    for (int mf = 0; mf < 4; ++mf) a4[mf] = *(const bf16x8*)(pa + mf * 512);
#pragma unroll
    for (int nf = 0; nf < 4; ++nf) br[nf] = *(const bf16x8*)(pb + nf * 512);
    if (stage) {
      stage_pair(c + 2);
      VMCNT(3);
    } else if (!last) {
      VMCNT(0);
    }
    __builtin_amdgcn_s_barrier();
    asm volatile("s_waitcnt lgkmcnt(0)" ::: "memory");
    __builtin_amdgcn_sched_barrier(0);
    __builtin_amdgcn_s_setprio(1);
#pragma unroll
    for (int mf = 0; mf < 4; ++mf)
#pragma unroll
      for (int nf = 0; nf < 4; ++nf)
        acc[mf][nf] = __builtin_amdgcn_mfma_f32_16x16x32_bf16(a4[mf], br[nf], acc[mf][nf], 0, 0, 0);
    __builtin_amdgcn_s_setprio(0);
    __builtin_amdgcn_s_barrier();
  };

  stage_pair(0);
  stage_pair(1);
  VMCNT(3);
  __builtin_amdgcn_s_barrier();

  for (int c = 0; c < NC - 2; ++c) phase(c, true, false);
  phase(NC - 2, false, false);   // VMCNT(0): drain pair(NC-1)
  phase(NC - 1, false, true);
}

// ---------------- QKV projection: (16384,3072) = Xb (16384,1024) * Wcat^T + bias ----------------
// 256x128 tiles -> 64 x 24 = 1536 blocks; XCD swizzle (1536%8==0). 2 blocks/CU target.
// Q, K stored (B,S,A) bf16; V stored TRANSPOSED as Vt (B,A,S) bf16.
__global__ __launch_bounds__(512, 4) void k_proj(const short* __restrict__ Xb, const short* __restrict__ Wc,
                                                 const float* __restrict__ biascat,
                                                 short* __restrict__ Q, short* __restrict__ K, short* __restrict__ Vt) {
  __shared__ __align__(16) short lds[36864];   // 72 KiB
  int tid = threadIdx.x;
  int wg = blockIdx.x;                         // 1536 blocks
  int swz = (wg & 7) * 192 + (wg >> 3);        // bijective XCD swizzle
  int mt = swz / 24, nt = swz % 24;
  int m0 = mt << 8, n0 = nt << 7;
  f32x4 acc[4][4] = {};
  gemm128n_core<1024, 1024>(Xb + (size_t)m0 * 1024, Wc + (size_t)n0 * 1024, 32, lds, acc, tid);
  int lane = tid & 63, wid = tid >> 6;
  int wm = wid >> 1, wn = wid & 1;
  int r15 = lane & 15, g = lane >> 4;
  int which = n0 >> 10;
  int nbase = n0 & 1023;
  if (which == 2) {
#pragma unroll
    for (int ni = 0; ni < 4; ++ni) {
      int cth = wn * 64 + ni * 16 + r15;
      int a = nbase + cth;
      float bv = biascat[n0 + cth];
#pragma unroll
      for (int mi = 0; mi < 4; ++mi) {
        int r = m0 + wm * 64 + mi * 16 + g * 4;
        int b = r >> 11, s = r & 2047;
        short4v o;
#pragma unroll
        for (int j = 0; j < 4; ++j) o[j] = f2bf(acc[mi][ni][j] + bv);
        *(short4v*)(Vt + ((size_t)b << 21) + ((size_t)a << 11) + s) = o;
      }
    }
  } else {
    short* outb = (which == 0) ? Q : K;
#pragma unroll
    for (int ni = 0; ni < 4; ++ni) {
      int cth = wn * 64 + ni * 16 + r15;
      float bv = biascat[n0 + cth];
#pragma unroll
      for (int mi = 0; mi < 4; ++mi)
#pragma unroll
        for (int j = 0; j < 4; ++j) {
          int r = m0 + wm * 64 + mi * 16 + g * 4 + j;
          outb[((size_t)r << 10) + nbase + cth] = f2bf(acc[mi][ni][j] + bv);
        }
    }
  }
}

// ---------------- QK^T: causal lower-tri 256-tiles, compact triangular grid (R8 core) ----------------
__global__ __launch_bounds__(512, 1) void k_qk(const short* __restrict__ Q, const short* __restrict__ K,
                                               short* __restrict__ Sc) {
  __shared__ __align__(16) short lds[65536];
  int f = blockIdx.x;                        // 0..287
  int swz = (f & 7) * 36 + (f >> 3);         // XCD x -> batch x
  int b = swz / 36;
  int t = swz % 36;
  int mt = (int)((sqrtf(8.f * t + 1.f) - 1.f) * 0.5f);
  while ((mt + 1) * (mt + 2) / 2 <= t) ++mt;
  while (mt * (mt + 1) / 2 > t) --mt;
  int nt = t - mt * (mt + 1) / 2;
  int tid = threadIdx.x;
  int m0 = mt << 8, n0 = nt << 8;
  const short* Qb = Q + ((size_t)b << 21);
  const short* Kb = K + ((size_t)b << 21);
  f32x4 acc[8][4] = {};
  gemm256_core<1024, 1024>(Qb + (size_t)m0 * 1024, Kb + (size_t)n0 * 1024, 16, lds, acc, tid);
  short* Sb = Sc + ((size_t)b << 22);
  int lane = tid & 63, wid = tid >> 6;
  int wm = wid >> 2, wn = wid & 3;
  int r15 = lane & 15;
#pragma unroll
  for (int mi = 0; mi < 8; ++mi)
#pragma unroll
    for (int ni = 0; ni < 4; ++ni)
#pragma unroll
      for (int j = 0; j < 4; ++j) {
        int r = m0 + wm * 128 + mi * 16 + ((lane >> 4) << 2) + j;
        int c = n0 + wn * 64 + ni * 16 + r15;
        Sb[((size_t)r << 11) + c] = f2bf(acc[mi][ni][j] * 0.03125f);
      }
}

// ---------------- row softmax in-place, causal; zero-fill to 256-tile edge ----------------
__global__ __launch_bounds__(256) void k_softmax(short* __restrict__ Sc) {
  int row = blockIdx.x;
  int b = row >> 11, q = row & 2047;
  short* Pr = Sc + ((size_t)b << 22) + ((size_t)q << 11);
  int T = ((q >> 8) + 1) << 8;
  int tid = threadIdx.x, lane = tid & 63, wid = tid >> 6;
  int k0 = tid << 3;
  float v[8];
  if (k0 < T) {
    short8v raw = *(const short8v*)(Pr + k0);
#pragma unroll
    for (int j = 0; j < 8; ++j) v[j] = (k0 + j <= q) ? bf2f(raw[j]) : -__builtin_inff();
  } else {
#pragma unroll
    for (int j = 0; j < 8; ++j) v[j] = -__builtin_inff();
  }
  float mx = v[0];
#pragma unroll
  for (int j = 1; j < 8; ++j) mx = fmaxf(mx, v[j]);
  for (int off = 1; off < 64; off <<= 1) mx = fmaxf(mx, __shfl_xor(mx, off, 64));
  __shared__ float red[2][4];
  if (lane == 0) red[0][wid] = mx;
  __syncthreads();
  mx = fmaxf(fmaxf(red[0][0], red[0][1]), fmaxf(red[0][2], red[0][3]));
  float e[8], sum = 0.f;
#pragma unroll
  for (int j = 0; j < 8; ++j) {
    e[j] = exp2f((v[j] - mx) * 1.4426950408889634f);
    sum += e[j];
  }
  for (int off = 1; off < 64; off <<= 1) sum += __shfl_xor(sum, off, 64);
  if (lane == 0) red[1][wid] = sum;
  __syncthreads();
  sum = red[1][0] + red[1][1] + red[1][2] + red[1][3];
  float inv = 1.f / sum;
  if (k0 < T) {
    short8v o;
#pragma unroll
    for (int j = 0; j < 8; ++j) o[j] = (k0 + j <= q) ? f2bf(e[j] * inv) : (short)0;
    *(short8v*)(Pr + k0) = o;
  }
}

// ---------------- PV: out (S,B,A) f32 = P (B,S,S) * Vt (B,A,S)^T (R8 core) ----------------
__global__ __launch_bounds__(512, 1) void k_pv(const short* __restrict__ P, const short* __restrict__ Vt,
                                               float* __restrict__ out) {
  __shared__ __align__(16) short lds[65536];
  int f = blockIdx.x;                        // 0..255
  int swz = (f & 7) * 32 + (f >> 3);         // XCD x -> batch x
  int nt = swz & 3;
  int mt = (swz >> 2) & 7;
  int b = swz >> 5;
  int tid = threadIdx.x;
  int m0 = mt << 8, n0 = nt << 8;
  const short* Pb = P + ((size_t)b << 22);
  const short* Vtb = Vt + ((size_t)b << 21);
  f32x4 acc[8][4] = {};
  gemm256_core<2048, 2048>(Pb + (size_t)m0 * 2048, Vtb + (size_t)n0 * 2048, 4 * (mt + 1), lds, acc, tid);
  int lane = tid & 63, wid = tid >> 6;
  int wm = wid >> 2, wn = wid & 3;
  int r15 = lane & 15;
#pragma unroll
  for (int mi = 0; mi < 8; ++mi)
#pragma unroll
    for (int ni = 0; ni < 4; ++ni)
#pragma unroll
      for (int j = 0; j < 4; ++j) {
        int r = m0 + wm * 128 + mi * 16 + ((lane >> 4) << 2) + j;  // q
        int c = n0 + wn * 64 + ni * 16 + r15;                      // a
        out[((size_t)r << 13) + ((size_t)b << 10) + c] = acc[mi][ni][j];
      }
}

extern "C" void kernel_launch(void* const* d_in, const int* in_sizes, int n_in,
                              void* d_out, int out_size, void* d_ws, size_t ws_size,
                              hipStream_t stream) {
  const float* x  = (const float*)d_in[0];
  const float* Wq = (const float*)d_in[1];
  const float* bq = (const float*)d_in[2];
  const float* Wk = (const float*)d_in[3];
  const float* bk = (const float*)d_in[4];
  const float* Wv = (const float*)d_in[5];
  const float* bv = (const float*)d_in[6];
  float* out = (float*)d_out;
  char* ws = (char*)d_ws;

  short* xb   = (short*)(ws);                    // 33,554,432 B
  short* Wcat = (short*)(ws + 33554432);         //  6,291,456 B
  float* bias = (float*)(ws + 39845888);         //     12,288 B
  short* Q    = (short*)(ws + 39858176);         // 33,554,432 B
  short* K    = (short*)(ws + 73412608);         // 33,554,432 B
  short* Vt   = (short*)(ws + 106967040);        // 33,554,432 B (written transposed by k_proj)
  short* Sc   = (short*)(ws + 140521472);        // 67,108,864 B

  k_cast_x<<<16384, 256, 0, stream>>>(x, xb);
  k_cast_w<<<3072, 256, 0, stream>>>(Wq, Wk, Wv, Wcat);
  k_cast_bias<<<12, 256, 0, stream>>>(bq, bk, bv, bias);
  k_proj<<<1536, 512, 0, stream>>>(xb, Wcat, bias, Q, K, Vt);
  k_qk<<<288, 512, 0, stream>>>(Q, K, Sc);
  k_softmax<<<16384, 256, 0, stream>>>(Sc);
  k_pv<<<256, 512, 0, stream>>>(Sc, Vt, out);
}

// Round 11
// 259.310 us; speedup vs baseline: 6.5978x; 1.0562x over previous
//
#include <hip/hip_runtime.h>
#include <hip/hip_bf16.h>
#include <math.h>

typedef short bf16x8 __attribute__((ext_vector_type(8)));
typedef float f32x4 __attribute__((ext_vector_type(4)));
typedef short short4v __attribute__((ext_vector_type(4)));
typedef short short8v __attribute__((ext_vector_type(8)));

__device__ __forceinline__ short f2bf(float f) {
  unsigned u = __builtin_bit_cast(unsigned, f);
  unsigned r = (u + 0x7FFFu + ((u >> 16) & 1u)) >> 16;
  return (short)r;
}
__device__ __forceinline__ float bf2f(short s) {
  unsigned u = ((unsigned)(unsigned short)s) << 16;
  return __builtin_bit_cast(float, u);
}

typedef __attribute__((address_space(1))) const unsigned g_u32;
typedef __attribute__((address_space(3))) unsigned l_u32;
__device__ __forceinline__ void gload_lds16(const short* g, short* l) {
  __builtin_amdgcn_global_load_lds((g_u32*)g, (l_u32*)l, 16, 0, 0);
}

#define VMCNT(n) asm volatile("s_waitcnt vmcnt(" #n ")" ::: "memory")

// ---------------- casts ----------------

__global__ __launch_bounds__(256) void k_cast_x(const float* __restrict__ x, short* __restrict__ xb) {
  int tid = blockIdx.x * 256 + threadIdx.x;
  int d4 = tid & 255;
  int sb = tid >> 8;
  int s = sb & 2047;
  int b = sb >> 11;
  float4 v = *((const float4*)(x + (((size_t)s * 8 + b) << 10)) + d4);
  short4v o;
  o.x = f2bf(v.x); o.y = f2bf(v.y); o.z = f2bf(v.z); o.w = f2bf(v.w);
  *((short4v*)(xb + (((size_t)b * 2048 + s) << 10)) + d4) = o;
}

__global__ __launch_bounds__(256) void k_cast_w(const float* __restrict__ Wq, const float* __restrict__ Wk,
                                                const float* __restrict__ Wv, short* __restrict__ Wcat) {
  int tid = blockIdx.x * 256 + threadIdx.x;
  int d4 = tid & 255;
  int n = tid >> 8;
  const float* src = (n < 1024) ? Wq : (n < 2048 ? Wk : Wv);
  int nl = n & 1023;
  float4 v = *((const float4*)(src + ((size_t)nl << 10)) + d4);
  short4v o;
  o.x = f2bf(v.x); o.y = f2bf(v.y); o.z = f2bf(v.z); o.w = f2bf(v.w);
  *((short4v*)(Wcat + ((size_t)n << 10)) + d4) = o;
}

__global__ __launch_bounds__(256) void k_cast_bias(const float* __restrict__ bq, const float* __restrict__ bk,
                                                   const float* __restrict__ bv, float* __restrict__ biascat) {
  int i = blockIdx.x * 256 + threadIdx.x;
  if (i < 3072) biascat[i] = (i < 1024) ? bq[i] : (i < 2048 ? bk[i & 1023] : bv[i & 1023]);
}

// ---------------- co-residency core (VERIFIED R10): 256x128 tile, 8 waves 4Mx2N ----------------
// acc[4][4]=64 regs; LDS = A-ring3 [256][32] + B-ring3 [128][32] = 72KB -> 2 blocks/CU.
// Per chunk c (ONE phase): {rd 4A+4B b128; stage pair(c+2) [2A+1B gload_lds]; VMCNT(3);
// barrier; lgkm; sched_barrier; 16 MFMA; barrier}. Prologue pair(0),pair(1),VMCNT(3);
// peel VMCNT(0) at c=NC-2. Slot swizzle slot^=(row>>1)&3 (0 conflicts, PMC-verified).
template <int LDA, int LDB>
__device__ __forceinline__ void gemm128n_core(const short* __restrict__ Ag, const short* __restrict__ Bg,
                                              int NC, short* __restrict__ lds, f32x4 (&acc)[4][4], int tid) {
  const int lane = tid & 63;
  const int wid = tid >> 6;
  const int wm = wid >> 1, wn = wid & 1;
  const int r15 = lane & 15;
  const int g = lane >> 4;
  const int co = ((g ^ ((r15 >> 1) & 3)) << 3);
  short* As = lds;                 // 3 x 8192 shorts
  short* Bs = lds + 3 * 8192;      // 3 x 4096 shorts

  const int abase = (wm * 64 + r15) * 32 + co;
  const int bbase = (wn * 64 + r15) * 32 + co;

  auto stage_pair = [&](int c) {   // A: 2 loads/thread; B: 1 load/thread
    short* Ap = As + (c % 3) * 8192;
    short* Bp = Bs + (c % 3) * 4096;
    int kb = c << 5;
#pragma unroll
    for (int i = 0; i < 2; ++i) {
      int ch = i * 512 + tid;
      int r = ch >> 2, s = ch & 3;
      gload_lds16(Ag + (size_t)r * LDA + kb + ((s ^ ((r >> 1) & 3)) << 3), Ap + ch * 8);
    }
    {
      int r = tid >> 2, s = tid & 3;
      gload_lds16(Bg + (size_t)r * LDB + kb + ((s ^ ((r >> 1) & 3)) << 3), Bp + tid * 8);
    }
  };

  auto phase = [&](int c, bool stage, bool last) {
    bf16x8 a4[4], br[4];
    const short* pa = As + (c % 3) * 8192 + abase;
    const short* pb = Bs + (c % 3) * 4096 + bbase;
#pragma unroll
    for (int mf = 0; mf < 4; ++mf) a4[mf] = *(const bf16x8*)(pa + mf * 512);
#pragma unroll
    for (int nf = 0; nf < 4; ++nf) br[nf] = *(const bf16x8*)(pb + nf * 512);
    if (stage) {
      stage_pair(c + 2);
      VMCNT(3);
    } else if (!last) {
      VMCNT(0);
    }
    __builtin_amdgcn_s_barrier();
    asm volatile("s_waitcnt lgkmcnt(0)" ::: "memory");
    __builtin_amdgcn_sched_barrier(0);
    __builtin_amdgcn_s_setprio(1);
#pragma unroll
    for (int mf = 0; mf < 4; ++mf)
#pragma unroll
      for (int nf = 0; nf < 4; ++nf)
        acc[mf][nf] = __builtin_amdgcn_mfma_f32_16x16x32_bf16(a4[mf], br[nf], acc[mf][nf], 0, 0, 0);
    __builtin_amdgcn_s_setprio(0);
    __builtin_amdgcn_s_barrier();
  };

  stage_pair(0);
  stage_pair(1);
  VMCNT(3);
  __builtin_amdgcn_s_barrier();

  for (int c = 0; c < NC - 2; ++c) phase(c, true, false);
  phase(NC - 2, false, false);   // VMCNT(0): drain pair(NC-1)
  phase(NC - 1, false, true);
}

// ---------------- QKV projection: (16384,3072) = Xb (16384,1024) * Wcat^T + bias ----------------
// 256x128 tiles -> 1536 blocks; XCD swizzle. Q,K (B,S,A) bf16; V transposed -> Vt (B,A,S).
__global__ __launch_bounds__(512, 4) void k_proj(const short* __restrict__ Xb, const short* __restrict__ Wc,
                                                 const float* __restrict__ biascat,
                                                 short* __restrict__ Q, short* __restrict__ K, short* __restrict__ Vt) {
  __shared__ __align__(16) short lds[36864];   // 72 KiB
  int tid = threadIdx.x;
  int wg = blockIdx.x;                         // 1536 blocks
  int swz = (wg & 7) * 192 + (wg >> 3);        // bijective XCD swizzle
  int mt = swz / 24, nt = swz % 24;
  int m0 = mt << 8, n0 = nt << 7;
  f32x4 acc[4][4] = {};
  gemm128n_core<1024, 1024>(Xb + (size_t)m0 * 1024, Wc + (size_t)n0 * 1024, 32, lds, acc, tid);
  int lane = tid & 63, wid = tid >> 6;
  int wm = wid >> 1, wn = wid & 1;
  int r15 = lane & 15, g = lane >> 4;
  int which = n0 >> 10;
  int nbase = n0 & 1023;
  if (which == 2) {
#pragma unroll
    for (int ni = 0; ni < 4; ++ni) {
      int cth = wn * 64 + ni * 16 + r15;
      int a = nbase + cth;
      float bv = biascat[n0 + cth];
#pragma unroll
      for (int mi = 0; mi < 4; ++mi) {
        int r = m0 + wm * 64 + mi * 16 + g * 4;
        int b = r >> 11, s = r & 2047;
        short4v o;
#pragma unroll
        for (int j = 0; j < 4; ++j) o[j] = f2bf(acc[mi][ni][j] + bv);
        *(short4v*)(Vt + ((size_t)b << 21) + ((size_t)a << 11) + s) = o;
      }
    }
  } else {
    short* outb = (which == 0) ? Q : K;
#pragma unroll
    for (int ni = 0; ni < 4; ++ni) {
      int cth = wn * 64 + ni * 16 + r15;
      float bv = biascat[n0 + cth];
#pragma unroll
      for (int mi = 0; mi < 4; ++mi)
#pragma unroll
        for (int j = 0; j < 4; ++j) {
          int r = m0 + wm * 64 + mi * 16 + g * 4 + j;
          outb[((size_t)r << 10) + nbase + cth] = f2bf(acc[mi][ni][j] + bv);
        }
    }
  }
}

// ---------------- QK^T: causal 256x128 tiles, co-resident core ----------------
// 576 blocks = 8 batches x 72 jobs; batch = XCD (f&7) for Q/K panel L2 locality.
// Jobs per mt: nt in [0, 2mt+1] (tiles covering k < 256-aligned causal bound).
__global__ __launch_bounds__(512, 4) void k_qk(const short* __restrict__ Q, const short* __restrict__ K,
                                               short* __restrict__ Sc) {
  __shared__ __align__(16) short lds[36864];
  int f = blockIdx.x;                        // 0..575
  int b = f & 7;                             // batch == XCD
  int idx = f >> 3;                          // 0..71; cum(mt) = mt(mt+1)
  int mt = (int)((sqrtf(4.f * idx + 1.f) - 1.f) * 0.5f);
  while ((mt + 1) * (mt + 2) <= idx) ++mt;
  while (mt * (mt + 1) > idx) --mt;
  int nt = idx - mt * (mt + 1);
  int tid = threadIdx.x;
  int m0 = mt << 8, n0 = nt << 7;
  const short* Qb = Q + ((size_t)b << 21);
  const short* Kb = K + ((size_t)b << 21);
  f32x4 acc[4][4] = {};
  gemm128n_core<1024, 1024>(Qb + (size_t)m0 * 1024, Kb + (size_t)n0 * 1024, 32, lds, acc, tid);
  short* Sb = Sc + ((size_t)b << 22);
  int lane = tid & 63, wid = tid >> 6;
  int wm = wid >> 1, wn = wid & 1;
  int r15 = lane & 15, g = lane >> 4;
#pragma unroll
  for (int mi = 0; mi < 4; ++mi)
#pragma unroll
    for (int ni = 0; ni < 4; ++ni)
#pragma unroll
      for (int j = 0; j < 4; ++j) {
        int r = m0 + wm * 64 + mi * 16 + g * 4 + j;
        int c = n0 + wn * 64 + ni * 16 + r15;
        Sb[((size_t)r << 11) + c] = f2bf(acc[mi][ni][j] * 0.03125f);
      }
}

// ---------------- row softmax in-place, causal; zero-fill to 256-tile edge ----------------
__global__ __launch_bounds__(256) void k_softmax(short* __restrict__ Sc) {
  int row = blockIdx.x;
  int b = row >> 11, q = row & 2047;
  short* Pr = Sc + ((size_t)b << 22) + ((size_t)q << 11);
  int T = ((q >> 8) + 1) << 8;
  int tid = threadIdx.x, lane = tid & 63, wid = tid >> 6;
  int k0 = tid << 3;
  float v[8];
  if (k0 < T) {
    short8v raw = *(const short8v*)(Pr + k0);
#pragma unroll
    for (int j = 0; j < 8; ++j) v[j] = (k0 + j <= q) ? bf2f(raw[j]) : -__builtin_inff();
  } else {
#pragma unroll
    for (int j = 0; j < 8; ++j) v[j] = -__builtin_inff();
  }
  float mx = v[0];
#pragma unroll
  for (int j = 1; j < 8; ++j) mx = fmaxf(mx, v[j]);
  for (int off = 1; off < 64; off <<= 1) mx = fmaxf(mx, __shfl_xor(mx, off, 64));
  __shared__ float red[2][4];
  if (lane == 0) red[0][wid] = mx;
  __syncthreads();
  mx = fmaxf(fmaxf(red[0][0], red[0][1]), fmaxf(red[0][2], red[0][3]));
  float e[8], sum = 0.f;
#pragma unroll
  for (int j = 0; j < 8; ++j) {
    e[j] = exp2f((v[j] - mx) * 1.4426950408889634f);
    sum += e[j];
  }
  for (int off = 1; off < 64; off <<= 1) sum += __shfl_xor(sum, off, 64);
  if (lane == 0) red[1][wid] = sum;
  __syncthreads();
  sum = red[1][0] + red[1][1] + red[1][2] + red[1][3];
  float inv = 1.f / sum;
  if (k0 < T) {
    short8v o;
#pragma unroll
    for (int j = 0; j < 8; ++j) o[j] = (k0 + j <= q) ? f2bf(e[j] * inv) : (short)0;
    *(short8v*)(Pr + k0) = o;
  }
}

// ---------------- PV: out (S,B,A) f32 = P (B,S,S) * Vt (B,A,S)^T ----------------
// 512 blocks = 8 batches x 64 jobs (mt 0..7 x nt 0..7, 256x128 tiles); batch = XCD.
// Complementary-mt pairing: within an XCD, idx and idx+32 get mt and 7-mt so each
// CU's two resident blocks sum to a constant 36 K-tiles (balance).
__global__ __launch_bounds__(512, 4) void k_pv(const short* __restrict__ P, const short* __restrict__ Vt,
                                               float* __restrict__ out) {
  __shared__ __align__(16) short lds[36864];
  int f = blockIdx.x;                        // 0..511
  int b = f & 7;                             // batch == XCD
  int idx = f >> 3;                          // 0..63
  int half = idx >> 5, j = idx & 31;
  int mt = half ? (7 - (j >> 2)) : (j >> 2);
  int nt = half ? (4 + (j & 3)) : (j & 3);
  int tid = threadIdx.x;
  int m0 = mt << 8, n0 = nt << 7;
  int NC = 8 * (mt + 1);
  const short* Pb = P + ((size_t)b << 22);
  const short* Vtb = Vt + ((size_t)b << 21);
  f32x4 acc[4][4] = {};
  gemm128n_core<2048, 2048>(Pb + (size_t)m0 * 2048, Vtb + (size_t)n0 * 2048, NC, lds, acc, tid);
  int lane = tid & 63, wid = tid >> 6;
  int wm = wid >> 1, wn = wid & 1;
  int r15 = lane & 15, g = lane >> 4;
#pragma unroll
  for (int mi = 0; mi < 4; ++mi)
#pragma unroll
    for (int ni = 0; ni < 4; ++ni)
#pragma unroll
      for (int j2 = 0; j2 < 4; ++j2) {
        int r = m0 + wm * 64 + mi * 16 + g * 4 + j2;   // q
        int c = n0 + wn * 64 + ni * 16 + r15;          // a
        out[((size_t)r << 13) + ((size_t)b << 10) + c] = acc[mi][ni][j2];
      }
}

extern "C" void kernel_launch(void* const* d_in, const int* in_sizes, int n_in,
                              void* d_out, int out_size, void* d_ws, size_t ws_size,
                              hipStream_t stream) {
  const float* x  = (const float*)d_in[0];
  const float* Wq = (const float*)d_in[1];
  const float* bq = (const float*)d_in[2];
  const float* Wk = (const float*)d_in[3];
  const float* bk = (const float*)d_in[4];
  const float* Wv = (const float*)d_in[5];
  const float* bv = (const float*)d_in[6];
  float* out = (float*)d_out;
  char* ws = (char*)d_ws;

  short* xb   = (short*)(ws);                    // 33,554,432 B
  short* Wcat = (short*)(ws + 33554432);         //  6,291,456 B
  float* bias = (float*)(ws + 39845888);         //     12,288 B
  short* Q    = (short*)(ws + 39858176);         // 33,554,432 B
  short* K    = (short*)(ws + 73412608);         // 33,554,432 B
  short* Vt   = (short*)(ws + 106967040);        // 33,554,432 B (written transposed by k_proj)
  short* Sc   = (short*)(ws + 140521472);        // 67,108,864 B

  k_cast_x<<<16384, 256, 0, stream>>>(x, xb);
  k_cast_w<<<3072, 256, 0, stream>>>(Wq, Wk, Wv, Wcat);
  k_cast_bias<<<12, 256, 0, stream>>>(bq, bk, bv, bias);
  k_proj<<<1536, 512, 0, stream>>>(xb, Wcat, bias, Q, K, Vt);
  k_qk<<<576, 512, 0, stream>>>(Q, K, Sc);
  k_softmax<<<16384, 256, 0, stream>>>(Sc);
  k_pv<<<512, 512, 0, stream>>>(Sc, Vt, out);
}

// Round 12
// 256.249 us; speedup vs baseline: 6.6766x; 1.0119x over previous
//
#include <hip/hip_runtime.h>
#include <hip/hip_bf16.h>
#include <math.h>

typedef short bf16x8 __attribute__((ext_vector_type(8)));
typedef float f32x4 __attribute__((ext_vector_type(4)));
typedef short short4v __attribute__((ext_vector_type(4)));
typedef short short8v __attribute__((ext_vector_type(8)));

__device__ __forceinline__ short f2bf(float f) {
  unsigned u = __builtin_bit_cast(unsigned, f);
  unsigned r = (u + 0x7FFFu + ((u >> 16) & 1u)) >> 16;
  return (short)r;
}
__device__ __forceinline__ float bf2f(short s) {
  unsigned u = ((unsigned)(unsigned short)s) << 16;
  return __builtin_bit_cast(float, u);
}

typedef __attribute__((address_space(1))) const unsigned g_u32;
typedef __attribute__((address_space(3))) unsigned l_u32;
__device__ __forceinline__ void gload_lds16(const short* g, short* l) {
  __builtin_amdgcn_global_load_lds((g_u32*)g, (l_u32*)l, 16, 0, 0);
}

#define VMCNT(n) asm volatile("s_waitcnt vmcnt(" #n ")" ::: "memory")

// ---------------- casts ----------------

__global__ __launch_bounds__(256) void k_cast_x(const float* __restrict__ x, short* __restrict__ xb) {
  int tid = blockIdx.x * 256 + threadIdx.x;
  int d4 = tid & 255;
  int sb = tid >> 8;
  int s = sb & 2047;
  int b = sb >> 11;
  float4 v = *((const float4*)(x + (((size_t)s * 8 + b) << 10)) + d4);
  short4v o;
  o.x = f2bf(v.x); o.y = f2bf(v.y); o.z = f2bf(v.z); o.w = f2bf(v.w);
  *((short4v*)(xb + (((size_t)b * 2048 + s) << 10)) + d4) = o;
}

__global__ __launch_bounds__(256) void k_cast_w(const float* __restrict__ Wq, const float* __restrict__ Wk,
                                                const float* __restrict__ Wv, short* __restrict__ Wcat) {
  int tid = blockIdx.x * 256 + threadIdx.x;
  int d4 = tid & 255;
  int n = tid >> 8;
  const float* src = (n < 1024) ? Wq : (n < 2048 ? Wk : Wv);
  int nl = n & 1023;
  float4 v = *((const float4*)(src + ((size_t)nl << 10)) + d4);
  short4v o;
  o.x = f2bf(v.x); o.y = f2bf(v.y); o.z = f2bf(v.z); o.w = f2bf(v.w);
  *((short4v*)(Wcat + ((size_t)n << 10)) + d4) = o;
}

__global__ __launch_bounds__(256) void k_cast_bias(const float* __restrict__ bq, const float* __restrict__ bk,
                                                   const float* __restrict__ bv, float* __restrict__ biascat) {
  int i = blockIdx.x * 256 + threadIdx.x;
  if (i < 3072) biascat[i] = (i < 1024) ? bq[i] : (i < 2048 ? bk[i & 1023] : bv[i & 1023]);
}

// ---------------- proj core: 256x256 tile, m201-style operand-hold, compiler-scheduled waits ----------------
// 512 threads = 8 waves (2M x 4N); per-wave 128x64 -> acc[8][4] (16x16x32 MFMA).
// LDS: per operand 4 K-half slots [256 rows][32 k] bf16 (2buf x 2kk) = 64KB; A+B = 128KB (1 block/CU).
// Slot swizzle slot^=(row>>1)&3 (0 conflicts, PMC-verified). Per K-tile(64): 4 phases x 16 MFMA:
//  ph1: rdA[mf0-3,kk0](4) + rdB[nf0-3,kk0](4); stageA(t+1,k0); bar; MFMA acc[0-3]; bar
//  ph2: rdA[mf4-7,kk0](4) [B held];            stageB(t+1,k0); VMCNT(4); bar; MFMA acc[4-7]; bar
//  ph3: rdA[mf0-3,kk1](4) + rdB[nf0-3,kk1](4); stageA(t+1,k1); bar; MFMA acc[0-3]; bar
//  ph4: rdA[mf4-7,kk1](4) [B held];            stageB(t+1,k1); VMCNT(4); bar; MFMA acc[4-7]; bar
// 24 ds_read_b128/tile/wave (B held across phase pairs). NO explicit lgkmcnt: reads are plain
// C++ loads; the compiler emits fine-grained lgkmcnt so MFMA starts when its operands land.
// Ledger (verified): steady invariant entering ph1(t): outstanding = {A(t,k1),B(t,k1)} (4 loads).
// VMCNT(4)@ph2 drains {A(t,k1),B(t,k1)} (needed ph3, issued 4 phases earlier), keeps t+1's k0 pair.
// VMCNT(4)@ph4 drains {A(t+1,k0),B(t+1,k0)} (needed ph1(t+1)), keeps t+1's k1 pair.
// Prologue: A(0,k0),B(0,k0),A(0,k1),B(0,k1); VMCNT(4) -> invariant holds at t=0.
// Last tile: no stages; VMCNT(0)@ph2 drains the final k1 pair.
template <int LDA, int LDB>
__device__ __forceinline__ void gemm256h_core(const short* __restrict__ Ag, const short* __restrict__ Bg,
                                              int NT, short* __restrict__ lds, f32x4 (&acc)[8][4], int tid) {
  const int lane = tid & 63;
  const int wid = tid >> 6;
  const int wm = wid >> 2, wn = wid & 3;
  const int r15 = lane & 15;
  const int g = lane >> 4;
  const int co = ((g ^ ((r15 >> 1) & 3)) << 3);
  short* As = lds;             // 4 slots x 8192 shorts
  short* Bs = lds + 32768;

  auto stageA = [&](int t, int kk) {
    short* Lp = As + (((t & 1) * 2 + kk) << 13);
    int kb = (t << 6) + (kk << 5);
#pragma unroll
    for (int i = 0; i < 2; ++i) {
      int ch = i * 512 + tid;
      int r = ch >> 2, s = ch & 3;
      gload_lds16(Ag + (size_t)r * LDA + kb + ((s ^ ((r >> 1) & 3)) << 3), Lp + ch * 8);
    }
  };
  auto stageB = [&](int t, int kk) {
    short* Lp = Bs + (((t & 1) * 2 + kk) << 13);
    int kb = (t << 6) + (kk << 5);
#pragma unroll
    for (int i = 0; i < 2; ++i) {
      int ch = i * 512 + tid;
      int r = ch >> 2, s = ch & 3;
      gload_lds16(Bg + (size_t)r * LDB + kb + ((s ^ ((r >> 1) & 3)) << 3), Lp + ch * 8);
    }
  };

  bf16x8 a4[4], br[4];
  auto rdA = [&](int t, int kk, int mh) {
    const short* p = As + (((t & 1) * 2 + kk) << 13) + (wm * 128 + mh * 64 + r15) * 32 + co;
#pragma unroll
    for (int mf = 0; mf < 4; ++mf) a4[mf] = *(const bf16x8*)(p + mf * 512);
  };
  auto rdB = [&](int t, int kk) {
    const short* p = Bs + (((t & 1) * 2 + kk) << 13) + (wn * 64 + r15) * 32 + co;
#pragma unroll
    for (int nf = 0; nf < 4; ++nf) br[nf] = *(const bf16x8*)(p + nf * 512);
  };
  auto mm = [&](int mh) {
    __builtin_amdgcn_s_setprio(1);
#pragma unroll
    for (int mf = 0; mf < 4; ++mf)
#pragma unroll
      for (int nf = 0; nf < 4; ++nf)
        acc[mh * 4 + mf][nf] =
            __builtin_amdgcn_mfma_f32_16x16x32_bf16(a4[mf], br[nf], acc[mh * 4 + mf][nf], 0, 0, 0);
    __builtin_amdgcn_s_setprio(0);
  };

  // prologue
  stageA(0, 0); stageB(0, 0); stageA(0, 1); stageB(0, 1);
  VMCNT(4);
  __builtin_amdgcn_s_barrier();

  for (int t = 0; t < NT; ++t) {
    const bool more = (t + 1 < NT);
    // ph1
    rdA(t, 0, 0); rdB(t, 0);
    if (more) stageA(t + 1, 0);
    __builtin_amdgcn_s_barrier();
    mm(0);
    __builtin_amdgcn_s_barrier();
    // ph2
    rdA(t, 0, 1);
    if (more) { stageB(t + 1, 0); VMCNT(4); } else { VMCNT(0); }
    __builtin_amdgcn_s_barrier();
    mm(1);
    __builtin_amdgcn_s_barrier();
    // ph3
    rdA(t, 1, 0); rdB(t, 1);
    if (more) stageA(t + 1, 1);
    __builtin_amdgcn_s_barrier();
    mm(0);
    __builtin_amdgcn_s_barrier();
    // ph4
    rdA(t, 1, 1);
    if (more) { stageB(t + 1, 1); VMCNT(4); }
    __builtin_amdgcn_s_barrier();
    mm(1);
    __builtin_amdgcn_s_barrier();
  }
}

// ---------------- co-residency core (VERIFIED R10/R11) ----------------
template <int LDA, int LDB>
__device__ __forceinline__ void gemm128n_core(const short* __restrict__ Ag, const short* __restrict__ Bg,
                                              int NC, short* __restrict__ lds, f32x4 (&acc)[4][4], int tid) {
  const int lane = tid & 63;
  const int wid = tid >> 6;
  const int wm = wid >> 1, wn = wid & 1;
  const int r15 = lane & 15;
  const int g = lane >> 4;
  const int co = ((g ^ ((r15 >> 1) & 3)) << 3);
  short* As = lds;                 // 3 x 8192 shorts
  short* Bs = lds + 3 * 8192;      // 3 x 4096 shorts

  const int abase = (wm * 64 + r15) * 32 + co;
  const int bbase = (wn * 64 + r15) * 32 + co;

  auto stage_pair = [&](int c) {
    short* Ap = As + (c % 3) * 8192;
    short* Bp = Bs + (c % 3) * 4096;
    int kb = c << 5;
#pragma unroll
    for (int i = 0; i < 2; ++i) {
      int ch = i * 512 + tid;
      int r = ch >> 2, s = ch & 3;
      gload_lds16(Ag + (size_t)r * LDA + kb + ((s ^ ((r >> 1) & 3)) << 3), Ap + ch * 8);
    }
    {
      int r = tid >> 2, s = tid & 3;
      gload_lds16(Bg + (size_t)r * LDB + kb + ((s ^ ((r >> 1) & 3)) << 3), Bp + tid * 8);
    }
  };

  auto phase = [&](int c, bool stage, bool last) {
    bf16x8 a4[4], br[4];
    const short* pa = As + (c % 3) * 8192 + abase;
    const short* pb = Bs + (c % 3) * 4096 + bbase;
#pragma unroll
    for (int mf = 0; mf < 4; ++mf) a4[mf] = *(const bf16x8*)(pa + mf * 512);
#pragma unroll
    for (int nf = 0; nf < 4; ++nf) br[nf] = *(const bf16x8*)(pb + nf * 512);
    if (stage) {
      stage_pair(c + 2);
      VMCNT(3);
    } else if (!last) {
      VMCNT(0);
    }
    __builtin_amdgcn_s_barrier();
    asm volatile("s_waitcnt lgkmcnt(0)" ::: "memory");
    __builtin_amdgcn_sched_barrier(0);
    __builtin_amdgcn_s_setprio(1);
#pragma unroll
    for (int mf = 0; mf < 4; ++mf)
#pragma unroll
      for (int nf = 0; nf < 4; ++nf)
        acc[mf][nf] = __builtin_amdgcn_mfma_f32_16x16x32_bf16(a4[mf], br[nf], acc[mf][nf], 0, 0, 0);
    __builtin_amdgcn_s_setprio(0);
    __builtin_amdgcn_s_barrier();
  };

  stage_pair(0);
  stage_pair(1);
  VMCNT(3);
  __builtin_amdgcn_s_barrier();

  for (int c = 0; c < NC - 2; ++c) phase(c, true, false);
  phase(NC - 2, false, false);
  phase(NC - 1, false, true);
}

// ---------------- QKV projection: new core ----------------
// 256x256 tiles -> 64 x 12 = 768 blocks; XCD swizzle. Q,K (B,S,A); V transposed -> Vt (B,A,S).
__global__ __launch_bounds__(512, 1) void k_proj(const short* __restrict__ Xb, const short* __restrict__ Wc,
                                                 const float* __restrict__ biascat,
                                                 short* __restrict__ Q, short* __restrict__ K, short* __restrict__ Vt) {
  __shared__ __align__(16) short lds[65536];
  int tid = threadIdx.x;
  int wg = blockIdx.x;                       // 768 blocks
  int swz = (wg & 7) * 96 + (wg >> 3);       // bijective XCD swizzle
  int mt = swz / 12, nt = swz % 12;
  int m0 = mt << 8, n0 = nt << 8;
  f32x4 acc[8][4] = {};
  gemm256h_core<1024, 1024>(Xb + (size_t)m0 * 1024, Wc + (size_t)n0 * 1024, 16, lds, acc, tid);
  int lane = tid & 63, wid = tid >> 6;
  int wm = wid >> 2, wn = wid & 3;
  int r15 = lane & 15, g = lane >> 4;
  int which = n0 >> 10;
  int nbase = n0 & 1023;
  if (which == 2) {
#pragma unroll
    for (int ni = 0; ni < 4; ++ni) {
      int cth = wn * 64 + ni * 16 + r15;
      int a = nbase + cth;
      float bv = biascat[n0 + cth];
#pragma unroll
      for (int mi = 0; mi < 8; ++mi) {
        int r = m0 + wm * 128 + (mi >> 2) * 64 + (mi & 3) * 16 + g * 4;
        int b = r >> 11, s = r & 2047;
        short4v o;
#pragma unroll
        for (int j = 0; j < 4; ++j) o[j] = f2bf(acc[mi][ni][j] + bv);
        *(short4v*)(Vt + ((size_t)b << 21) + ((size_t)a << 11) + s) = o;
      }
    }
  } else {
    short* outb = (which == 0) ? Q : K;
#pragma unroll
    for (int ni = 0; ni < 4; ++ni) {
      int cth = wn * 64 + ni * 16 + r15;
      float bv = biascat[n0 + cth];
#pragma unroll
      for (int mi = 0; mi < 8; ++mi)
#pragma unroll
        for (int j = 0; j < 4; ++j) {
          int r = m0 + wm * 128 + (mi >> 2) * 64 + (mi & 3) * 16 + g * 4 + j;
          outb[((size_t)r << 10) + nbase + cth] = f2bf(acc[mi][ni][j] + bv);
        }
    }
  }
}

// ---------------- QK^T (VERIFIED R11): causal 256x128 tiles, co-resident core ----------------
__global__ __launch_bounds__(512, 4) void k_qk(const short* __restrict__ Q, const short* __restrict__ K,
                                               short* __restrict__ Sc) {
  __shared__ __align__(16) short lds[36864];
  int f = blockIdx.x;                        // 0..575
  int b = f & 7;                             // batch == XCD
  int idx = f >> 3;                          // 0..71
  int mt = (int)((sqrtf(4.f * idx + 1.f) - 1.f) * 0.5f);
  while ((mt + 1) * (mt + 2) <= idx) ++mt;
  while (mt * (mt + 1) > idx) --mt;
  int nt = idx - mt * (mt + 1);
  int tid = threadIdx.x;
  int m0 = mt << 8, n0 = nt << 7;
  const short* Qb = Q + ((size_t)b << 21);
  const short* Kb = K + ((size_t)b << 21);
  f32x4 acc[4][4] = {};
  gemm128n_core<1024, 1024>(Qb + (size_t)m0 * 1024, Kb + (size_t)n0 * 1024, 32, lds, acc, tid);
  short* Sb = Sc + ((size_t)b << 22);
  int lane = tid & 63, wid = tid >> 6;
  int wm = wid >> 1, wn = wid & 1;
  int r15 = lane & 15, g = lane >> 4;
#pragma unroll
  for (int mi = 0; mi < 4; ++mi)
#pragma unroll
    for (int ni = 0; ni < 4; ++ni)
#pragma unroll
      for (int j = 0; j < 4; ++j) {
        int r = m0 + wm * 64 + mi * 16 + g * 4 + j;
        int c = n0 + wn * 64 + ni * 16 + r15;
        Sb[((size_t)r << 11) + c] = f2bf(acc[mi][ni][j] * 0.03125f);
      }
}

// ---------------- row softmax: one WAVE per row, no LDS, causal; zero-fill to 256 edge ----------------
__global__ __launch_bounds__(256) void k_softmax(short* __restrict__ Sc) {
  int row = blockIdx.x * 4 + (threadIdx.x >> 6);   // 4096 blocks x 4 waves
  int lane = threadIdx.x & 63;
  int b = row >> 11, q = row & 2047;
  short* Pr = Sc + ((size_t)b << 22) + ((size_t)q << 11);
  int T = ((q >> 8) + 1) << 8;          // padded causal length (multiple of 256)
  float v[4][8];
  float mx = -__builtin_inff();
#pragma unroll
  for (int it = 0; it < 4; ++it) {
    int k0 = it * 512 + lane * 8;
    if (k0 < T) {
      short8v raw = *(const short8v*)(Pr + k0);
#pragma unroll
      for (int j = 0; j < 8; ++j) {
        float x = (k0 + j <= q) ? bf2f(raw[j]) : -__builtin_inff();
        v[it][j] = x;
        mx = fmaxf(mx, x);
      }
    }
  }
  for (int off = 1; off < 64; off <<= 1) mx = fmaxf(mx, __shfl_xor(mx, off, 64));
  float sum = 0.f;
#pragma unroll
  for (int it = 0; it < 4; ++it) {
    int k0 = it * 512 + lane * 8;
    if (k0 < T) {
#pragma unroll
      for (int j = 0; j < 8; ++j) {
        float e = exp2f((v[it][j] - mx) * 1.4426950408889634f);
        v[it][j] = e;
        sum += e;
      }
    }
  }
  for (int off = 1; off < 64; off <<= 1) sum += __shfl_xor(sum, off, 64);
  float inv = 1.f / sum;
#pragma unroll
  for (int it = 0; it < 4; ++it) {
    int k0 = it * 512 + lane * 8;
    if (k0 < T) {
      short8v o;
#pragma unroll
      for (int j = 0; j < 8; ++j) o[j] = (k0 + j <= q) ? f2bf(v[it][j] * inv) : (short)0;
      *(short8v*)(Pr + k0) = o;
    }
  }
}

// ---------------- PV (VERIFIED R11): co-resident core, complementary-mt pairing ----------------
__global__ __launch_bounds__(512, 4) void k_pv(const short* __restrict__ P, const short* __restrict__ Vt,
                                               float* __restrict__ out) {
  __shared__ __align__(16) short lds[36864];
  int f = blockIdx.x;                        // 0..511
  int b = f & 7;                             // batch == XCD
  int idx = f >> 3;                          // 0..63
  int half = idx >> 5, j = idx & 31;
  int mt = half ? (7 - (j >> 2)) : (j >> 2);
  int nt = half ? (4 + (j & 3)) : (j & 3);
  int tid = threadIdx.x;
  int m0 = mt << 8, n0 = nt << 7;
  int NC = 8 * (mt + 1);
  const short* Pb = P + ((size_t)b << 22);
  const short* Vtb = Vt + ((size_t)b << 21);
  f32x4 acc[4][4] = {};
  gemm128n_core<2048, 2048>(Pb + (size_t)m0 * 2048, Vtb + (size_t)n0 * 2048, NC, lds, acc, tid);
  int lane = tid & 63, wid = tid >> 6;
  int wm = wid >> 1, wn = wid & 1;
  int r15 = lane & 15, g = lane >> 4;
#pragma unroll
  for (int mi = 0; mi < 4; ++mi)
#pragma unroll
    for (int ni = 0; ni < 4; ++ni)
#pragma unroll
      for (int j2 = 0; j2 < 4; ++j2) {
        int r = m0 + wm * 64 + mi * 16 + g * 4 + j2;   // q
        int c = n0 + wn * 64 + ni * 16 + r15;          // a
        out[((size_t)r << 13) + ((size_t)b << 10) + c] = acc[mi][ni][j2];
      }
}

extern "C" void kernel_launch(void* const* d_in, const int* in_sizes, int n_in,
                              void* d_out, int out_size, void* d_ws, size_t ws_size,
                              hipStream_t stream) {
  const float* x  = (const float*)d_in[0];
  const float* Wq = (const float*)d_in[1];
  const float* bq = (const float*)d_in[2];
  const float* Wk = (const float*)d_in[3];
  const float* bk = (const float*)d_in[4];
  const float* Wv = (const float*)d_in[5];
  const float* bv = (const float*)d_in[6];
  float* out = (float*)d_out;
  char* ws = (char*)d_ws;

  short* xb   = (short*)(ws);                    // 33,554,432 B
  short* Wcat = (short*)(ws + 33554432);         //  6,291,456 B
  float* bias = (float*)(ws + 39845888);         //     12,288 B
  short* Q    = (short*)(ws + 39858176);         // 33,554,432 B
  short* K    = (short*)(ws + 73412608);         // 33,554,432 B
  short* Vt   = (short*)(ws + 106967040);        // 33,554,432 B (written transposed by k_proj)
  short* Sc   = (short*)(ws + 140521472);        // 67,108,864 B

  k_cast_x<<<16384, 256, 0, stream>>>(x, xb);
  k_cast_w<<<3072, 256, 0, stream>>>(Wq, Wk, Wv, Wcat);
  k_cast_bias<<<12, 256, 0, stream>>>(bq, bk, bv, bias);
  k_proj<<<768, 512, 0, stream>>>(xb, Wcat, bias, Q, K, Vt);
  k_qk<<<576, 512, 0, stream>>>(Q, K, Sc);
  k_softmax<<<4096, 256, 0, stream>>>(Sc);
  k_pv<<<512, 512, 0, stream>>>(Sc, Vt, out);
}